// Round 8
// baseline (284.829 us; speedup 1.0000x reference)
//
#include <hip/hip_runtime.h>
#include <hip/hip_bf16.h>

#define IN_DIM 128
#define HH 8
#define DD 16
#define HD 128   // H*D
#define SCAN_B 256
#define BCHUNK 4096  // edges per bucketize tail block

#define MT  64   // nodes per proj block
#define KP  136  // padded K stride for Wt (bf16 elems)
#define NCH 128  // output-channel chunk staged in LDS

typedef float f32x4 __attribute__((ext_vector_type(4)));
typedef short s16x8 __attribute__((ext_vector_type(8)));

// ---------------------------------------------------------------------------
// dtype sniff helper: returns 1 if h is fp32 storage, 0 if bf16.
// ---------------------------------------------------------------------------
__device__ __forceinline__ int sniff_fp32(const unsigned short* h_raw) {
  int sane = 0;
#pragma unroll
  for (int i = 0; i < 128; i += 2) {
    const unsigned short u = h_raw[i];
    const int expo = (u >> 7) & 0xFF;
    if (expo >= 112 && expo <= 143) sane++;
  }
  return (sane >= 40) ? 0 : 1;
}

// ---------------------------------------------------------------------------
// Kernel 1: W^T staging (self-sniffing).  Wt[n][k] bf16, n in [0,384),
// padded stride KP.  Block 0 publishes the dtype flag and zeroes
// bucket_cur (258 ints) -- no memset launch on the hot path.
// ---------------------------------------------------------------------------
__global__ __launch_bounds__(128) void wt_kernel(
    const unsigned short* __restrict__ h_raw,
    const void* __restrict__ Wq, const void* __restrict__ Wk,
    const void* __restrict__ Wv, __hip_bfloat16* __restrict__ Wt,
    int* __restrict__ flag, int* __restrict__ bucket_cur) {
  const int isf = sniff_fp32(h_raw);  // block-uniform, ~64 L2-hit loads
  const int n = blockIdx.x;
  const int k = threadIdx.x;
  if (n == 0) {
    if (k == 0) *flag = isf;
    for (int j = k; j < 258; j += 128) bucket_cur[j] = 0;
  }
  const int mat = n >> 7;
  const int col = n & 127;
  const void* W = (mat == 0) ? Wq : (mat == 1) ? Wk : Wv;
  float v;
  if (isf) v = ((const float*)W)[(size_t)k * HD + col];
  else     v = __bfloat162float(((const __hip_bfloat16*)W)[(size_t)k * HD + col]);
  Wt[(size_t)n * KP + k] = __float2bfloat16(v);
}

// ---------------------------------------------------------------------------
// Kernel 2 (fused): blocks [0,pgrid) = MFMA projection; blocks
// [pgrid, pgrid+nchunkB) = capacity-slotted bucketize.
// Bucket b owns ebuf slot [b*ecap, (b+1)*ecap); final bucket_cur[b] is
// the bucket size consumed by csr.  Q stored bf16 (Qb).  K and V
// interleaved into KVb[node][256].
// ---------------------------------------------------------------------------
__global__ __launch_bounds__(256) void proj_bucketize_kernel(
    const void* __restrict__ h, const __hip_bfloat16* __restrict__ Wt,
    const void* __restrict__ bq, const void* __restrict__ bk,
    const void* __restrict__ bv,
    __hip_bfloat16* __restrict__ Qb, __hip_bfloat16* __restrict__ KVb,
    const int* __restrict__ flag, int n_nodes,
    const int* __restrict__ src, const int* __restrict__ dst,
    int* __restrict__ bucket_cur, unsigned int* __restrict__ ebuf,
    int ecap, int n_edges, int pgrid) {
  __shared__ short Bs[NCH * KP];
  __shared__ short As[MT * KP];

  const int tid = threadIdx.x;

  if (blockIdx.x >= pgrid) {
    // ---- bucketize role (capacity-slotted, no hist needed) ----
    int* lh = (int*)Bs;
    const int e0 = (blockIdx.x - pgrid) * BCHUNK;
    const int e1 = (e0 + BCHUNK < n_edges) ? e0 + BCHUNK : n_edges;
    lh[tid] = 0;
    __syncthreads();
    for (int e = e0 + tid; e < e1; e += 256) atomicAdd(&lh[dst[e] >> 8], 1);
    __syncthreads();
    const int cnt_local = lh[tid];
    int base = 0;
    if (cnt_local > 0)
      base = tid * ecap + atomicAdd(&bucket_cur[tid], cnt_local);
    __syncthreads();
    lh[tid] = base;
    __syncthreads();
    for (int e = e0 + tid; e < e1; e += 256) {
      const int d = dst[e];
      const int pos = atomicAdd(&lh[d >> 8], 1);
      ebuf[pos] = ((unsigned int)src[e] << 16) | (unsigned int)d;
    }
    return;
  }

  // ---- projection role ----
  const int node0 = blockIdx.x * MT;
  const int isf = *flag;

#pragma unroll
  for (int j = 0; j < 16; ++j) {
    const int pid = tid + j * 256;
    const int m = pid >> 6;
    const int kk = (pid & 63) * 2;
    const int g = node0 + m;
    unsigned int pack = 0;
    if (g < n_nodes) {
      if (isf) {
        const float2 f2 = *(const float2*)((const float*)h + (size_t)g * HD + kk);
        const __hip_bfloat16 b0 = __float2bfloat16(f2.x);
        const __hip_bfloat16 b1 = __float2bfloat16(f2.y);
        pack = (unsigned int)(*(const unsigned short*)&b0) |
               ((unsigned int)(*(const unsigned short*)&b1) << 16);
      } else {
        pack = *(const unsigned int*)((const __hip_bfloat16*)h +
                                      (size_t)g * HD + kk);
      }
    }
    *(unsigned int*)&As[m * KP + kk] = pack;
  }
  __syncthreads();

  const int wave = tid >> 6;
  const int lane = tid & 63;
  const int l15 = lane & 15;
  const int quad = lane >> 4;

  s16x8 afrag[4];
#pragma unroll
  for (int k4 = 0; k4 < 4; ++k4)
    afrag[k4] = *(const s16x8*)&As[(wave * 16 + l15) * KP + k4 * 32 + quad * 8];

  for (int c = 0; c < 3; ++c) {
    __syncthreads();
    const uint4* gsrc = (const uint4*)(Wt + (size_t)c * NCH * KP);
    for (int j = tid; j < (NCH * KP * 2) / 16; j += 256)
      ((uint4*)Bs)[j] = gsrc[j];
    __syncthreads();

    f32x4 acc[8];
#pragma unroll
    for (int t = 0; t < 8; ++t) acc[t] = (f32x4){0.f, 0.f, 0.f, 0.f};

#pragma unroll
    for (int t = 0; t < 8; ++t) {
#pragma unroll
      for (int k4 = 0; k4 < 4; ++k4) {
        const s16x8 bfrag =
            *(const s16x8*)&Bs[(t * 16 + l15) * KP + k4 * 32 + quad * 8];
        acc[t] = __builtin_amdgcn_mfma_f32_16x16x32_bf16(afrag[k4], bfrag,
                                                         acc[t], 0, 0, 0);
      }
    }

    const void* bp = (c == 0) ? bq : (c == 1) ? bk : bv;
#pragma unroll
    for (int t = 0; t < 8; ++t) {
      const int ncol = t * 16 + l15;
      const float bias = isf ? ((const float*)bp)[ncol]
                             : __bfloat162float(((const __hip_bfloat16*)bp)[ncol]);
#pragma unroll
      for (int r = 0; r < 4; ++r) {
        const int g = node0 + wave * 16 + quad * 4 + r;
        if (g < n_nodes) {
          const float val = acc[t][r] + bias;
          if (c == 0) {
            Qb[(size_t)g * HD + ncol] = __float2bfloat16(val);
          } else if (c == 1) {
            KVb[(size_t)g * 256 + ncol] = __float2bfloat16(val);
          } else {
            KVb[(size_t)g * 256 + 128 + ncol] = __float2bfloat16(val);
          }
        }
      }
    }
  }
}

// ---------------------------------------------------------------------------
// Fused pass B: per-bucket count -> LDS scan -> row_ptr -> LDS-cursor
// scatter (512 threads).  Bucket sizes from bucket_cur; bucket b's edges
// live at ebuf[b*ecap ...).
// ---------------------------------------------------------------------------
__global__ __launch_bounds__(512) void bucket_csr_kernel(
    const unsigned int* __restrict__ ebuf, const int* __restrict__ bucket_cur,
    int* __restrict__ row_ptr, int* __restrict__ edge_src,
    int n_nodes, int nbuck, int ecap, int n_edges) {
  __shared__ int lc[256];
  __shared__ int sh[256];
  const int b = blockIdx.x;
  const int t = threadIdx.x;

  // exclusive scan of bucket sizes to find this bucket's output base
  int v = 0;
  if (t < 256) {
    v = (t < nbuck) ? bucket_cur[t] : 0;
    sh[t] = v;
  }
  __syncthreads();
  for (int off = 1; off < 256; off <<= 1) {
    int add = 0;
    if (t < 256 && t >= off) add = sh[t - off];
    __syncthreads();
    if (t < 256) sh[t] += add;
    __syncthreads();
  }
  if (t < 256) lc[t] = sh[t] - v;  // publish exclusive prefixes
  __syncthreads();
  const int lo_out = lc[b];              // base in edge_src (global CSR)
  const int size_b = bucket_cur[b];
  const int lo_in = b * ecap;            // base in ebuf (capacity slot)
  const int nbase = b << 8;
  __syncthreads();

  if (t < 256) lc[t] = 0;
  __syncthreads();
  for (int i = t; i < size_b; i += 512)
    atomicAdd(&lc[(ebuf[lo_in + i] & 0xFFFFu) - nbase], 1);
  __syncthreads();

  int v2 = 0;
  if (t < 256) {
    v2 = lc[t];
    sh[t] = v2;
  }
  __syncthreads();
  for (int off = 1; off < 256; off <<= 1) {
    int add = 0;
    if (t < 256 && t >= off) add = sh[t - off];
    __syncthreads();
    if (t < 256) sh[t] += add;
    __syncthreads();
  }
  const int excl = (t < 256) ? (sh[t] - v2) : 0;

  if (t < 256) {
    const int node = nbase + t;
    if (node < n_nodes) row_ptr[node] = lo_out + excl;
    if (b == nbuck - 1 && t == 255) row_ptr[n_nodes] = n_edges;
  }
  __syncthreads();
  if (t < 256) lc[t] = lo_out + excl;
  __syncthreads();
  for (int i = t; i < size_b; i += 512) {
    const unsigned int pkd = ebuf[lo_in + i];
    const int pos = atomicAdd(&lc[(pkd & 0xFFFFu) - nbase], 1);
    edge_src[pos] = (int)(pkd >> 16);
  }
}

// ---------------------------------------------------------------------------
// Fallback CSR build (n_nodes > 65536): direct hist + scans + scatter.
// ---------------------------------------------------------------------------
__global__ __launch_bounds__(256) void hist_kernel(
    const int* __restrict__ dst, int* __restrict__ cnt, int n_edges) {
  const int e = blockIdx.x * blockDim.x + threadIdx.x;
  if (e < n_edges) atomicAdd(&cnt[dst[e]], 1);
}

__global__ __launch_bounds__(256) void scatter_kernel(
    const int* __restrict__ src, const int* __restrict__ dst,
    int* __restrict__ cursor, int* __restrict__ edge_src, int n_edges) {
  const int e = blockIdx.x * blockDim.x + threadIdx.x;
  if (e < n_edges) {
    const int pos = atomicAdd(&cursor[dst[e]], 1);
    edge_src[pos] = src[e];
  }
}

__global__ __launch_bounds__(SCAN_B) void scan1_kernel(
    const int* __restrict__ cnt, int* __restrict__ exs,
    int* __restrict__ bsum, int n) {
  __shared__ int sh[SCAN_B];
  const int t = threadIdx.x;
  const int i = blockIdx.x * SCAN_B + t;
  int v = (i < n) ? cnt[i] : 0;
  sh[t] = v;
  __syncthreads();
  for (int off = 1; off < SCAN_B; off <<= 1) {
    int add = (t >= off) ? sh[t - off] : 0;
    __syncthreads();
    sh[t] += add;
    __syncthreads();
  }
  if (i < n) exs[i] = sh[t] - v;
  if (t == SCAN_B - 1) bsum[blockIdx.x] = sh[t];
}

__global__ __launch_bounds__(SCAN_B) void scan2_kernel(int* __restrict__ bsum,
                                                       int nb) {
  __shared__ int sh[SCAN_B];
  const int t = threadIdx.x;
  if (nb <= SCAN_B) {
    int v = (t < nb) ? bsum[t] : 0;
    sh[t] = v;
    __syncthreads();
    for (int off = 1; off < SCAN_B; off <<= 1) {
      int add = (t >= off) ? sh[t - off] : 0;
      __syncthreads();
      sh[t] += add;
      __syncthreads();
    }
    if (t < nb) bsum[t] = sh[t] - v;
  } else if (t == 0) {
    int run = 0;
    for (int b = 0; b < nb; ++b) { int v = bsum[b]; bsum[b] = run; run += v; }
  }
}

__global__ __launch_bounds__(SCAN_B) void scan3_kernel(
    const int* __restrict__ exs, const int* __restrict__ bsum,
    int* __restrict__ row_ptr, int* __restrict__ cursor, int n, int n_edges) {
  const int i = blockIdx.x * SCAN_B + threadIdx.x;
  if (i < n) {
    const int v = exs[i] + bsum[blockIdx.x];
    row_ptr[i] = v;
    cursor[i] = v;
  }
  if (i == 0) row_ptr[n] = n_edges;
}

// ---------------------------------------------------------------------------
// Kernel 3: per-destination gather (logic unchanged; round-8 adds node0 so
// the grid can be split into two unequal dispatches -- any middle kernel
// longer than the larger half must then surface in the profiler's top-5).
// ---------------------------------------------------------------------------
__global__ __launch_bounds__(128) void gather_kernel(
    const int* __restrict__ row_ptr, const int* __restrict__ edge_src,
    const __hip_bfloat16* __restrict__ Qb, const __hip_bfloat16* __restrict__ KVb,
    void* __restrict__ out, const int* __restrict__ flag, int n_nodes,
    int node0) {
  __shared__ float vred[HD][17];   // channel-major partials, pad 17 (8704B)
  __shared__ float zred[16][HH];   // edge-slot x head z partials

  const int d = node0 + blockIdx.x;
  const int tid = threadIdx.x;

  const int eloc = tid >> 3;   // edge slot 0..15
  const int hh8  = tid & 7;    // head 0..7

  const int start = row_ptr[d];
  const int deg = row_ptr[d + 1] - start;

  // Q row slice for this head (bf16 -> f32), pre-scaled by 1/sqrt(D)
  float qreg[16];
  {
    const uint4* qp = (const uint4*)(Qb + (size_t)d * HD + hh8 * 16);
    unsigned int qw[8];
    *(uint4*)&qw[0] = qp[0];
    *(uint4*)&qw[4] = qp[1];
#pragma unroll
    for (int i = 0; i < 8; ++i) {
      qreg[2 * i]     = __uint_as_float(qw[i] << 16) * 0.25f;
      qreg[2 * i + 1] = __uint_as_float(qw[i] & 0xFFFF0000u) * 0.25f;
    }
  }

  float acc[16];
#pragma unroll
  for (int j = 0; j < 16; ++j) acc[j] = 0.0f;
  float zacc = 0.0f;

  // prefetch both edge slots' src indices
  int s0 = 0, s1 = 0;
  if (eloc < deg) s0 = edge_src[start + eloc];
  if (eloc + 16 < deg) s1 = edge_src[start + eloc + 16];

  for (int ei = eloc; ei < deg; ei += 32) {
    const int sA = s0;
    const bool hasB = (ei + 16 < deg);
    const int sB = hasB ? s1 : sA;  // clamp to a valid row for the loads

    const int nx = ei + 32;
    if (nx < deg) s0 = edge_src[start + nx];
    if (nx + 16 < deg) s1 = edge_src[start + nx + 16];

    // issue all 8 x 16B loads up front (K and V interleaved per node).
    const uint4* pA = (const uint4*)(KVb + (size_t)sA * 256 + hh8 * 16);
    const uint4* pB = (const uint4*)(KVb + (size_t)sB * 256 + hh8 * 16);
    const uint4 kA0 = pA[0], kA1 = pA[1];
    const uint4 vA0 = pA[16], vA1 = pA[17];  // +128 bf16 = +256B = +16 uint4
    const uint4 kB0 = pB[0], kB1 = pB[1];
    const uint4 vB0 = pB[16], vB1 = pB[17];

    unsigned int kw[8];
    *(uint4*)&kw[0] = kA0;
    *(uint4*)&kw[4] = kA1;
    float dotA = 0.0f;
#pragma unroll
    for (int i = 0; i < 8; ++i) {
      const float klo = __uint_as_float(kw[i] << 16);
      const float khi = __uint_as_float(kw[i] & 0xFFFF0000u);
      dotA = fmaf(qreg[2 * i], klo, dotA);
      dotA = fmaf(qreg[2 * i + 1], khi, dotA);
    }
    *(uint4*)&kw[0] = kB0;
    *(uint4*)&kw[4] = kB1;
    float dotB = 0.0f;
#pragma unroll
    for (int i = 0; i < 8; ++i) {
      const float klo = __uint_as_float(kw[i] << 16);
      const float khi = __uint_as_float(kw[i] & 0xFFFF0000u);
      dotB = fmaf(qreg[2 * i], klo, dotB);
      dotB = fmaf(qreg[2 * i + 1], khi, dotB);
    }
    const float scoreA = __expf(fminf(fmaxf(dotA, -5.0f), 5.0f));
    float scoreB = __expf(fminf(fmaxf(dotB, -5.0f), 5.0f));
    if (!hasB) scoreB = 0.0f;
    zacc += scoreA + scoreB;

    unsigned int vwA[8], vwB[8];
    *(uint4*)&vwA[0] = vA0;
    *(uint4*)&vwA[4] = vA1;
    *(uint4*)&vwB[0] = vB0;
    *(uint4*)&vwB[4] = vB1;
#pragma unroll
    for (int i = 0; i < 8; ++i) {
      const float vAlo = __uint_as_float(vwA[i] << 16);
      const float vAhi = __uint_as_float(vwA[i] & 0xFFFF0000u);
      const float vBlo = __uint_as_float(vwB[i] << 16);
      const float vBhi = __uint_as_float(vwB[i] & 0xFFFF0000u);
      acc[2 * i]     = fmaf(scoreA, vAlo, acc[2 * i]);
      acc[2 * i]     = fmaf(scoreB, vBlo, acc[2 * i]);
      acc[2 * i + 1] = fmaf(scoreA, vAhi, acc[2 * i + 1]);
      acc[2 * i + 1] = fmaf(scoreB, vBhi, acc[2 * i + 1]);
    }
  }

  // publish partials channel-major
#pragma unroll
  for (int j = 0; j < 16; ++j) vred[hh8 * 16 + j][eloc] = acc[j];
  zred[eloc][hh8] = zacc;
  __syncthreads();

  // thread = output channel tid; reduce over 16 edge slots
  const int hd16 = tid >> 4;
  float sumV = 0.0f;
#pragma unroll
  for (int i = 0; i < 16; ++i) sumV += vred[tid][i];
  float sumZ = 0.0f;
#pragma unroll
  for (int i = 0; i < 16; ++i) sumZ += zred[i][hd16];

  const float r = sumV / (sumZ + 1e-6f);
  const size_t o = (size_t)d * HD + tid;
  if (*flag) ((float*)out)[o] = r;
  else       ((__hip_bfloat16*)out)[o] = __float2bfloat16(r);
}

// ---------------------------------------------------------------------------
extern "C" void kernel_launch(void* const* d_in, const int* in_sizes, int n_in,
                              void* d_out, int out_size, void* d_ws, size_t ws_size,
                              hipStream_t stream) {
  const void* h  = d_in[0];
  const void* Wq = d_in[1];
  const void* bq = d_in[2];
  const void* Wk = d_in[3];
  const void* bk = d_in[4];
  const void* Wv = d_in[5];
  const void* bv = d_in[6];
  const int* src = (const int*)d_in[7];
  const int* dst = (const int*)d_in[8];

  const int n_nodes = in_sizes[0] / IN_DIM;  // 50000
  const int n_edges = in_sizes[7];           // 1600000
  const int nb = (n_nodes + SCAN_B - 1) / SCAN_B;
  const int nbuck = (n_nodes + 255) >> 8;

  // bucket capacity slot: 2x mean size, 256-aligned, >= 4096
  int ecap = ((2 * (n_edges / (nbuck > 0 ? nbuck : 1)) + 255) / 256) * 256;
  if (ecap < 4096) ecap = 4096;

  // workspace layout (256B-aligned chunks)
  char* p = (char*)d_ws;
  int* flag = (int*)p;                       p += 256;
  __hip_bfloat16* Qb = (__hip_bfloat16*)p;   p += (size_t)n_nodes * HD * 2;
  __hip_bfloat16* KVb = (__hip_bfloat16*)p;  p += (size_t)n_nodes * 256 * 2;
  __hip_bfloat16* Wt = (__hip_bfloat16*)p;   p += ((size_t)384 * KP * 2 + 255) / 256 * 256;
  int* bucket_cur = (int*)p;                 p += 258 * 4 + 248;  // 256B-align next
  int* row_ptr = (int*)p;                    p += (size_t)(n_nodes + 1 + 63) / 64 * 64 * 4;
  int* edge_src = (int*)p;                   p += (size_t)n_edges * 4;
  unsigned int* ebuf = (unsigned int*)p;     p += (size_t)nbuck * ecap * 4;
  // fallback-only arrays
  int* cnt = (int*)p;                        p += (size_t)n_nodes * 4;
  int* exs = (int*)p;                        p += (size_t)n_nodes * 4;
  int* bsum = (int*)p;                       p += (size_t)(nb + 1) * 4;
  int* cursor = (int*)p;                     p += (size_t)n_nodes * 4;

  // wt: self-sniffs, publishes flag, zeroes bucket_cur
  wt_kernel<<<384, 128, 0, stream>>>((const unsigned short*)h, Wq, Wk, Wv, Wt,
                                     flag, bucket_cur);

  const int pgrid = (n_nodes + MT - 1) / MT;
  const int nchunkB = (n_edges + BCHUNK - 1) / BCHUNK;

  if (n_nodes <= 65536) {
    // fused proj + capacity-slotted bucketize (no hist pass at all)
    proj_bucketize_kernel<<<pgrid + nchunkB, 256, 0, stream>>>(
        h, Wt, bq, bk, bv, Qb, KVb, flag, n_nodes, src, dst, bucket_cur,
        ebuf, ecap, n_edges, pgrid);
    bucket_csr_kernel<<<nbuck, 512, 0, stream>>>(ebuf, bucket_cur, row_ptr,
                                                 edge_src, n_nodes, nbuck,
                                                 ecap, n_edges);
  } else {
    // fallback: proj alone, then direct hist + scans + scatter
    proj_bucketize_kernel<<<pgrid, 256, 0, stream>>>(
        h, Wt, bq, bk, bv, Qb, KVb, flag, n_nodes, src, dst, bucket_cur,
        ebuf, ecap, n_edges, pgrid);
    hipMemsetAsync(cnt, 0, (size_t)n_nodes * sizeof(int), stream);
    const int eb = 256;
    const int egrid = (n_edges + eb - 1) / eb;
    hist_kernel<<<egrid, eb, 0, stream>>>(dst, cnt, n_edges);
    scan1_kernel<<<nb, SCAN_B, 0, stream>>>(cnt, exs, bsum, n_nodes);
    scan2_kernel<<<1, SCAN_B, 0, stream>>>(bsum, nb);
    scan3_kernel<<<nb, SCAN_B, 0, stream>>>(exs, bsum, row_ptr, cursor,
                                            n_nodes, n_edges);
    scatter_kernel<<<egrid, eb, 0, stream>>>(src, dst, cursor, edge_src,
                                             n_edges);
  }

  // gather split into two unequal dispatches (diagnostic round-8): any
  // middle dispatch longer than the large half (~2/3 of gather) must now
  // appear in the profiler's top-5 with full counters.
  if (n_nodes > 20000) {
    const int split = 18000;
    gather_kernel<<<split, 128, 0, stream>>>(row_ptr, edge_src, Qb, KVb,
                                             d_out, flag, n_nodes, 0);
    gather_kernel<<<n_nodes - split, 128, 0, stream>>>(
        row_ptr, edge_src, Qb, KVb, d_out, flag, n_nodes, split);
  } else {
    gather_kernel<<<n_nodes, 128, 0, stream>>>(row_ptr, edge_src, Qb, KVb,
                                               d_out, flag, n_nodes, 0);
  }
}

// Round 9
// 277.322 us; speedup vs baseline: 1.0271x; 1.0271x over previous
//
#include <hip/hip_runtime.h>
#include <hip/hip_bf16.h>

#define IN_DIM 128
#define HH 8
#define DD 16
#define HD 128   // H*D
#define SCAN_B 256
#define BCHUNK 4096  // edges per bucketize block

#define MT  64   // nodes per proj block
#define KP  136  // padded K stride for Wt (bf16 elems)
#define NCH 128  // output channels per matrix

typedef float f32x4 __attribute__((ext_vector_type(4)));
typedef short s16x8 __attribute__((ext_vector_type(8)));

// ---------------------------------------------------------------------------
// dtype sniff helper: returns 1 if h is fp32 storage, 0 if bf16.
// ---------------------------------------------------------------------------
__device__ __forceinline__ int sniff_fp32(const unsigned short* h_raw) {
  int sane = 0;
#pragma unroll
  for (int i = 0; i < 128; i += 2) {
    const unsigned short u = h_raw[i];
    const int expo = (u >> 7) & 0xFF;
    if (expo >= 112 && expo <= 143) sane++;
  }
  return (sane >= 40) ? 0 : 1;
}

// ---------------------------------------------------------------------------
// Kernel 1: W^T staging (self-sniffing).  Wt[n][k] bf16, n in [0,384),
// padded stride KP.  Block 0 publishes the dtype flag and zeroes
// bucket_cur (258 ints) -- no memset launch on the hot path.
// ---------------------------------------------------------------------------
__global__ __launch_bounds__(128) void wt_kernel(
    const unsigned short* __restrict__ h_raw,
    const void* __restrict__ Wq, const void* __restrict__ Wk,
    const void* __restrict__ Wv, __hip_bfloat16* __restrict__ Wt,
    int* __restrict__ flag, int* __restrict__ bucket_cur) {
  const int isf = sniff_fp32(h_raw);  // block-uniform, ~64 L2-hit loads
  const int n = blockIdx.x;
  const int k = threadIdx.x;
  if (n == 0) {
    if (k == 0) *flag = isf;
    for (int j = k; j < 258; j += 128) bucket_cur[j] = 0;
  }
  const int mat = n >> 7;
  const int col = n & 127;
  const void* W = (mat == 0) ? Wq : (mat == 1) ? Wk : Wv;
  float v;
  if (isf) v = ((const float*)W)[(size_t)k * HD + col];
  else     v = __bfloat162float(((const __hip_bfloat16*)W)[(size_t)k * HD + col]);
  Wt[(size_t)n * KP + k] = __float2bfloat16(v);
}

// ---------------------------------------------------------------------------
// Kernel 2 (fused, round-9): blocks [0, nchunkB) = capacity-slotted
// bucketize (FIRST, so they co-run with proj from t=0); blocks
// [nchunkB, nchunkB+pgrid) = MFMA projection.
// Round-9 proj changes: NO Bs staging -- B-fragments are read directly
// from the L2-resident Wt (all blocks share the same 104 KB; per-block
// LDS restaging was 81 MB of redundant copies behind 6 barriers).  LDS
// drops 52->18.4 KB; __launch_bounds__(256,4) targets 16 waves/CU.
// ---------------------------------------------------------------------------
__global__ __launch_bounds__(256, 4) void proj_bucketize_kernel(
    const void* __restrict__ h, const __hip_bfloat16* __restrict__ Wt,
    const void* __restrict__ bq, const void* __restrict__ bk,
    const void* __restrict__ bv,
    __hip_bfloat16* __restrict__ Qb, __hip_bfloat16* __restrict__ KVb,
    const int* __restrict__ flag, int n_nodes,
    const int* __restrict__ src, const int* __restrict__ dst,
    int* __restrict__ bucket_cur, unsigned int* __restrict__ ebuf,
    int ecap, int n_edges, int nchunkB) {
  __shared__ short As[MT * KP];
  __shared__ int lh[256];

  const int tid = threadIdx.x;

  if (blockIdx.x < nchunkB) {
    // ---- bucketize role (capacity-slotted, runs concurrent with proj) ----
    const int e0 = blockIdx.x * BCHUNK;
    const int e1 = (e0 + BCHUNK < n_edges) ? e0 + BCHUNK : n_edges;
    lh[tid] = 0;
    __syncthreads();
    for (int e = e0 + tid; e < e1; e += 256) atomicAdd(&lh[dst[e] >> 8], 1);
    __syncthreads();
    const int cnt_local = lh[tid];
    int base = 0;
    if (cnt_local > 0)
      base = tid * ecap + atomicAdd(&bucket_cur[tid], cnt_local);
    __syncthreads();
    lh[tid] = base;
    __syncthreads();
    for (int e = e0 + tid; e < e1; e += 256) {
      const int d = dst[e];
      const int pos = atomicAdd(&lh[d >> 8], 1);
      ebuf[pos] = ((unsigned int)src[e] << 16) | (unsigned int)d;
    }
    return;
  }

  // ---- projection role ----
  const int node0 = (blockIdx.x - nchunkB) * MT;
  const int isf = *flag;

#pragma unroll
  for (int j = 0; j < 16; ++j) {
    const int pid = tid + j * 256;
    const int m = pid >> 6;
    const int kk = (pid & 63) * 2;
    const int g = node0 + m;
    unsigned int pack = 0;
    if (g < n_nodes) {
      if (isf) {
        const float2 f2 = *(const float2*)((const float*)h + (size_t)g * HD + kk);
        const __hip_bfloat16 b0 = __float2bfloat16(f2.x);
        const __hip_bfloat16 b1 = __float2bfloat16(f2.y);
        pack = (unsigned int)(*(const unsigned short*)&b0) |
               ((unsigned int)(*(const unsigned short*)&b1) << 16);
      } else {
        pack = *(const unsigned int*)((const __hip_bfloat16*)h +
                                      (size_t)g * HD + kk);
      }
    }
    *(unsigned int*)&As[m * KP + kk] = pack;
  }
  __syncthreads();

  const int wave = tid >> 6;
  const int lane = tid & 63;
  const int l15 = lane & 15;
  const int quad = lane >> 4;

  s16x8 afrag[4];
#pragma unroll
  for (int k4 = 0; k4 < 4; ++k4)
    afrag[k4] = *(const s16x8*)&As[(wave * 16 + l15) * KP + k4 * 32 + quad * 8];

  for (int c = 0; c < 3; ++c) {
    // B-fragments straight from L2-resident Wt (no LDS staging, no barriers)
    const __hip_bfloat16* Wc = Wt + (size_t)c * NCH * KP;

    f32x4 acc[8];
#pragma unroll
    for (int t = 0; t < 8; ++t) acc[t] = (f32x4){0.f, 0.f, 0.f, 0.f};

#pragma unroll
    for (int t = 0; t < 8; ++t) {
#pragma unroll
      for (int k4 = 0; k4 < 4; ++k4) {
        const s16x8 bfrag = *(const s16x8*)(
            Wc + (t * 16 + l15) * KP + k4 * 32 + quad * 8);
        acc[t] = __builtin_amdgcn_mfma_f32_16x16x32_bf16(afrag[k4], bfrag,
                                                         acc[t], 0, 0, 0);
      }
    }

    const void* bp = (c == 0) ? bq : (c == 1) ? bk : bv;
#pragma unroll
    for (int t = 0; t < 8; ++t) {
      const int ncol = t * 16 + l15;
      const float bias = isf ? ((const float*)bp)[ncol]
                             : __bfloat162float(((const __hip_bfloat16*)bp)[ncol]);
#pragma unroll
      for (int r = 0; r < 4; ++r) {
        const int g = node0 + wave * 16 + quad * 4 + r;
        if (g < n_nodes) {
          const float val = acc[t][r] + bias;
          if (c == 0) {
            Qb[(size_t)g * HD + ncol] = __float2bfloat16(val);
          } else if (c == 1) {
            KVb[(size_t)g * 256 + ncol] = __float2bfloat16(val);
          } else {
            KVb[(size_t)g * 256 + 128 + ncol] = __float2bfloat16(val);
          }
        }
      }
    }
  }
}

// ---------------------------------------------------------------------------
// Fused pass B: per-bucket count -> LDS scan -> row_ptr -> LDS-cursor
// scatter (512 threads).  Bucket sizes from bucket_cur; bucket b's edges
// live at ebuf[b*ecap ...).
// ---------------------------------------------------------------------------
__global__ __launch_bounds__(512) void bucket_csr_kernel(
    const unsigned int* __restrict__ ebuf, const int* __restrict__ bucket_cur,
    int* __restrict__ row_ptr, int* __restrict__ edge_src,
    int n_nodes, int nbuck, int ecap, int n_edges) {
  __shared__ int lc[256];
  __shared__ int sh[256];
  const int b = blockIdx.x;
  const int t = threadIdx.x;

  // exclusive scan of bucket sizes to find this bucket's output base
  int v = 0;
  if (t < 256) {
    v = (t < nbuck) ? bucket_cur[t] : 0;
    sh[t] = v;
  }
  __syncthreads();
  for (int off = 1; off < 256; off <<= 1) {
    int add = 0;
    if (t < 256 && t >= off) add = sh[t - off];
    __syncthreads();
    if (t < 256) sh[t] += add;
    __syncthreads();
  }
  if (t < 256) lc[t] = sh[t] - v;  // publish exclusive prefixes
  __syncthreads();
  const int lo_out = lc[b];              // base in edge_src (global CSR)
  const int size_b = bucket_cur[b];
  const int lo_in = b * ecap;            // base in ebuf (capacity slot)
  const int nbase = b << 8;
  __syncthreads();

  if (t < 256) lc[t] = 0;
  __syncthreads();
  for (int i = t; i < size_b; i += 512)
    atomicAdd(&lc[(ebuf[lo_in + i] & 0xFFFFu) - nbase], 1);
  __syncthreads();

  int v2 = 0;
  if (t < 256) {
    v2 = lc[t];
    sh[t] = v2;
  }
  __syncthreads();
  for (int off = 1; off < 256; off <<= 1) {
    int add = 0;
    if (t < 256 && t >= off) add = sh[t - off];
    __syncthreads();
    if (t < 256) sh[t] += add;
    __syncthreads();
  }
  const int excl = (t < 256) ? (sh[t] - v2) : 0;

  if (t < 256) {
    const int node = nbase + t;
    if (node < n_nodes) row_ptr[node] = lo_out + excl;
    if (b == nbuck - 1 && t == 255) row_ptr[n_nodes] = n_edges;
  }
  __syncthreads();
  if (t < 256) lc[t] = lo_out + excl;
  __syncthreads();
  for (int i = t; i < size_b; i += 512) {
    const unsigned int pkd = ebuf[lo_in + i];
    const int pos = atomicAdd(&lc[(pkd & 0xFFFFu) - nbase], 1);
    edge_src[pos] = (int)(pkd >> 16);
  }
}

// ---------------------------------------------------------------------------
// Fallback CSR build (n_nodes > 65536): direct hist + scans + scatter.
// ---------------------------------------------------------------------------
__global__ __launch_bounds__(256) void hist_kernel(
    const int* __restrict__ dst, int* __restrict__ cnt, int n_edges) {
  const int e = blockIdx.x * blockDim.x + threadIdx.x;
  if (e < n_edges) atomicAdd(&cnt[dst[e]], 1);
}

__global__ __launch_bounds__(256) void scatter_kernel(
    const int* __restrict__ src, const int* __restrict__ dst,
    int* __restrict__ cursor, int* __restrict__ edge_src, int n_edges) {
  const int e = blockIdx.x * blockDim.x + threadIdx.x;
  if (e < n_edges) {
    const int pos = atomicAdd(&cursor[dst[e]], 1);
    edge_src[pos] = src[e];
  }
}

__global__ __launch_bounds__(SCAN_B) void scan1_kernel(
    const int* __restrict__ cnt, int* __restrict__ exs,
    int* __restrict__ bsum, int n) {
  __shared__ int sh[SCAN_B];
  const int t = threadIdx.x;
  const int i = blockIdx.x * SCAN_B + t;
  int v = (i < n) ? cnt[i] : 0;
  sh[t] = v;
  __syncthreads();
  for (int off = 1; off < SCAN_B; off <<= 1) {
    int add = (t >= off) ? sh[t - off] : 0;
    __syncthreads();
    sh[t] += add;
    __syncthreads();
  }
  if (i < n) exs[i] = sh[t] - v;
  if (t == SCAN_B - 1) bsum[blockIdx.x] = sh[t];
}

__global__ __launch_bounds__(SCAN_B) void scan2_kernel(int* __restrict__ bsum,
                                                       int nb) {
  __shared__ int sh[SCAN_B];
  const int t = threadIdx.x;
  if (nb <= SCAN_B) {
    int v = (t < nb) ? bsum[t] : 0;
    sh[t] = v;
    __syncthreads();
    for (int off = 1; off < SCAN_B; off <<= 1) {
      int add = (t >= off) ? sh[t - off] : 0;
      __syncthreads();
      sh[t] += add;
      __syncthreads();
    }
    if (t < nb) bsum[t] = sh[t] - v;
  } else if (t == 0) {
    int run = 0;
    for (int b = 0; b < nb; ++b) { int v = bsum[b]; bsum[b] = run; run += v; }
  }
}

__global__ __launch_bounds__(SCAN_B) void scan3_kernel(
    const int* __restrict__ exs, const int* __restrict__ bsum,
    int* __restrict__ row_ptr, int* __restrict__ cursor, int n, int n_edges) {
  const int i = blockIdx.x * SCAN_B + threadIdx.x;
  if (i < n) {
    const int v = exs[i] + bsum[blockIdx.x];
    row_ptr[i] = v;
    cursor[i] = v;
  }
  if (i == 0) row_ptr[n] = n_edges;
}

// ---------------------------------------------------------------------------
// Kernel 3: per-destination gather (unchanged; split into two unequal
// dispatches -- measured free, keeps middle kernels visible in top-5).
// ---------------------------------------------------------------------------
__global__ __launch_bounds__(128) void gather_kernel(
    const int* __restrict__ row_ptr, const int* __restrict__ edge_src,
    const __hip_bfloat16* __restrict__ Qb, const __hip_bfloat16* __restrict__ KVb,
    void* __restrict__ out, const int* __restrict__ flag, int n_nodes,
    int node0) {
  __shared__ float vred[HD][17];   // channel-major partials, pad 17 (8704B)
  __shared__ float zred[16][HH];   // edge-slot x head z partials

  const int d = node0 + blockIdx.x;
  const int tid = threadIdx.x;

  const int eloc = tid >> 3;   // edge slot 0..15
  const int hh8  = tid & 7;    // head 0..7

  const int start = row_ptr[d];
  const int deg = row_ptr[d + 1] - start;

  // Q row slice for this head (bf16 -> f32), pre-scaled by 1/sqrt(D)
  float qreg[16];
  {
    const uint4* qp = (const uint4*)(Qb + (size_t)d * HD + hh8 * 16);
    unsigned int qw[8];
    *(uint4*)&qw[0] = qp[0];
    *(uint4*)&qw[4] = qp[1];
#pragma unroll
    for (int i = 0; i < 8; ++i) {
      qreg[2 * i]     = __uint_as_float(qw[i] << 16) * 0.25f;
      qreg[2 * i + 1] = __uint_as_float(qw[i] & 0xFFFF0000u) * 0.25f;
    }
  }

  float acc[16];
#pragma unroll
  for (int j = 0; j < 16; ++j) acc[j] = 0.0f;
  float zacc = 0.0f;

  // prefetch both edge slots' src indices
  int s0 = 0, s1 = 0;
  if (eloc < deg) s0 = edge_src[start + eloc];
  if (eloc + 16 < deg) s1 = edge_src[start + eloc + 16];

  for (int ei = eloc; ei < deg; ei += 32) {
    const int sA = s0;
    const bool hasB = (ei + 16 < deg);
    const int sB = hasB ? s1 : sA;  // clamp to a valid row for the loads

    const int nx = ei + 32;
    if (nx < deg) s0 = edge_src[start + nx];
    if (nx + 16 < deg) s1 = edge_src[start + nx + 16];

    // issue all 8 x 16B loads up front (K and V interleaved per node).
    const uint4* pA = (const uint4*)(KVb + (size_t)sA * 256 + hh8 * 16);
    const uint4* pB = (const uint4*)(KVb + (size_t)sB * 256 + hh8 * 16);
    const uint4 kA0 = pA[0], kA1 = pA[1];
    const uint4 vA0 = pA[16], vA1 = pA[17];  // +128 bf16 = +256B = +16 uint4
    const uint4 kB0 = pB[0], kB1 = pB[1];
    const uint4 vB0 = pB[16], vB1 = pB[17];

    unsigned int kw[8];
    *(uint4*)&kw[0] = kA0;
    *(uint4*)&kw[4] = kA1;
    float dotA = 0.0f;
#pragma unroll
    for (int i = 0; i < 8; ++i) {
      const float klo = __uint_as_float(kw[i] << 16);
      const float khi = __uint_as_float(kw[i] & 0xFFFF0000u);
      dotA = fmaf(qreg[2 * i], klo, dotA);
      dotA = fmaf(qreg[2 * i + 1], khi, dotA);
    }
    *(uint4*)&kw[0] = kB0;
    *(uint4*)&kw[4] = kB1;
    float dotB = 0.0f;
#pragma unroll
    for (int i = 0; i < 8; ++i) {
      const float klo = __uint_as_float(kw[i] << 16);
      const float khi = __uint_as_float(kw[i] & 0xFFFF0000u);
      dotB = fmaf(qreg[2 * i], klo, dotB);
      dotB = fmaf(qreg[2 * i + 1], khi, dotB);
    }
    const float scoreA = __expf(fminf(fmaxf(dotA, -5.0f), 5.0f));
    float scoreB = __expf(fminf(fmaxf(dotB, -5.0f), 5.0f));
    if (!hasB) scoreB = 0.0f;
    zacc += scoreA + scoreB;

    unsigned int vwA[8], vwB[8];
    *(uint4*)&vwA[0] = vA0;
    *(uint4*)&vwA[4] = vA1;
    *(uint4*)&vwB[0] = vB0;
    *(uint4*)&vwB[4] = vB1;
#pragma unroll
    for (int i = 0; i < 8; ++i) {
      const float vAlo = __uint_as_float(vwA[i] << 16);
      const float vAhi = __uint_as_float(vwA[i] & 0xFFFF0000u);
      const float vBlo = __uint_as_float(vwB[i] << 16);
      const float vBhi = __uint_as_float(vwB[i] & 0xFFFF0000u);
      acc[2 * i]     = fmaf(scoreA, vAlo, acc[2 * i]);
      acc[2 * i]     = fmaf(scoreB, vBlo, acc[2 * i]);
      acc[2 * i + 1] = fmaf(scoreA, vAhi, acc[2 * i + 1]);
      acc[2 * i + 1] = fmaf(scoreB, vBhi, acc[2 * i + 1]);
    }
  }

  // publish partials channel-major
#pragma unroll
  for (int j = 0; j < 16; ++j) vred[hh8 * 16 + j][eloc] = acc[j];
  zred[eloc][hh8] = zacc;
  __syncthreads();

  // thread = output channel tid; reduce over 16 edge slots
  const int hd16 = tid >> 4;
  float sumV = 0.0f;
#pragma unroll
  for (int i = 0; i < 16; ++i) sumV += vred[tid][i];
  float sumZ = 0.0f;
#pragma unroll
  for (int i = 0; i < 16; ++i) sumZ += zred[i][hd16];

  const float r = sumV / (sumZ + 1e-6f);
  const size_t o = (size_t)d * HD + tid;
  if (*flag) ((float*)out)[o] = r;
  else       ((__hip_bfloat16*)out)[o] = __float2bfloat16(r);
}

// ---------------------------------------------------------------------------
extern "C" void kernel_launch(void* const* d_in, const int* in_sizes, int n_in,
                              void* d_out, int out_size, void* d_ws, size_t ws_size,
                              hipStream_t stream) {
  const void* h  = d_in[0];
  const void* Wq = d_in[1];
  const void* bq = d_in[2];
  const void* Wk = d_in[3];
  const void* bk = d_in[4];
  const void* Wv = d_in[5];
  const void* bv = d_in[6];
  const int* src = (const int*)d_in[7];
  const int* dst = (const int*)d_in[8];

  const int n_nodes = in_sizes[0] / IN_DIM;  // 50000
  const int n_edges = in_sizes[7];           // 1600000
  const int nb = (n_nodes + SCAN_B - 1) / SCAN_B;
  const int nbuck = (n_nodes + 255) >> 8;

  // bucket capacity slot: 2x mean size, 256-aligned, >= 4096
  int ecap = ((2 * (n_edges / (nbuck > 0 ? nbuck : 1)) + 255) / 256) * 256;
  if (ecap < 4096) ecap = 4096;

  // workspace layout (256B-aligned chunks)
  char* p = (char*)d_ws;
  int* flag = (int*)p;                       p += 256;
  __hip_bfloat16* Qb = (__hip_bfloat16*)p;   p += (size_t)n_nodes * HD * 2;
  __hip_bfloat16* KVb = (__hip_bfloat16*)p;  p += (size_t)n_nodes * 256 * 2;
  __hip_bfloat16* Wt = (__hip_bfloat16*)p;   p += ((size_t)384 * KP * 2 + 255) / 256 * 256;
  int* bucket_cur = (int*)p;                 p += 258 * 4 + 248;  // 256B-align next
  int* row_ptr = (int*)p;                    p += (size_t)(n_nodes + 1 + 63) / 64 * 64 * 4;
  int* edge_src = (int*)p;                   p += (size_t)n_edges * 4;
  unsigned int* ebuf = (unsigned int*)p;     p += (size_t)nbuck * ecap * 4;
  // fallback-only arrays
  int* cnt = (int*)p;                        p += (size_t)n_nodes * 4;
  int* exs = (int*)p;                        p += (size_t)n_nodes * 4;
  int* bsum = (int*)p;                       p += (size_t)(nb + 1) * 4;
  int* cursor = (int*)p;                     p += (size_t)n_nodes * 4;

  // wt: self-sniffs, publishes flag, zeroes bucket_cur
  wt_kernel<<<384, 128, 0, stream>>>((const unsigned short*)h, Wq, Wk, Wv, Wt,
                                     flag, bucket_cur);

  const int pgrid = (n_nodes + MT - 1) / MT;
  const int nchunkB = (n_edges + BCHUNK - 1) / BCHUNK;

  if (n_nodes <= 65536) {
    // fused bucketize-first + proj (bucketize co-runs with proj from t=0)
    proj_bucketize_kernel<<<nchunkB + pgrid, 256, 0, stream>>>(
        h, Wt, bq, bk, bv, Qb, KVb, flag, n_nodes, src, dst, bucket_cur,
        ebuf, ecap, n_edges, nchunkB);
    bucket_csr_kernel<<<nbuck, 512, 0, stream>>>(ebuf, bucket_cur, row_ptr,
                                                 edge_src, n_nodes, nbuck,
                                                 ecap, n_edges);
  } else {
    // fallback: proj alone (nchunkB=0), then direct hist + scans + scatter
    proj_bucketize_kernel<<<pgrid, 256, 0, stream>>>(
        h, Wt, bq, bk, bv, Qb, KVb, flag, n_nodes, src, dst, bucket_cur,
        ebuf, ecap, n_edges, 0);
    hipMemsetAsync(cnt, 0, (size_t)n_nodes * sizeof(int), stream);
    const int eb = 256;
    const int egrid = (n_edges + eb - 1) / eb;
    hist_kernel<<<egrid, eb, 0, stream>>>(dst, cnt, n_edges);
    scan1_kernel<<<nb, SCAN_B, 0, stream>>>(cnt, exs, bsum, n_nodes);
    scan2_kernel<<<1, SCAN_B, 0, stream>>>(bsum, nb);
    scan3_kernel<<<nb, SCAN_B, 0, stream>>>(exs, bsum, row_ptr, cursor,
                                            n_nodes, n_edges);
    scatter_kernel<<<egrid, eb, 0, stream>>>(src, dst, cursor, edge_src,
                                             n_edges);
  }

  // gather split into two unequal dispatches (measured free; keeps middle
  // kernels visible in the profiler's top-5)
  if (n_nodes > 20000) {
    const int split = 18000;
    gather_kernel<<<split, 128, 0, stream>>>(row_ptr, edge_src, Qb, KVb,
                                             d_out, flag, n_nodes, 0);
    gather_kernel<<<n_nodes - split, 128, 0, stream>>>(
        row_ptr, edge_src, Qb, KVb, d_out, flag, n_nodes, split);
  } else {
    gather_kernel<<<n_nodes, 128, 0, stream>>>(row_ptr, edge_src, Qb, KVb,
                                               d_out, flag, n_nodes, 0);
  }
}

// Round 11
// 268.252 us; speedup vs baseline: 1.0618x; 1.0338x over previous
//
#include <hip/hip_runtime.h>
#include <hip/hip_bf16.h>

#define IN_DIM 128
#define HH 8
#define DD 16
#define HD 128   // H*D
#define SCAN_B 256
#define BCHUNK 4096  // edges per bucketize block

#define MT  32   // nodes per proj block (round-10: halved for 2x block count)
#define KP  136  // padded K stride for Wt (bf16 elems)
#define NCH 128  // output channels per matrix

typedef float f32x4 __attribute__((ext_vector_type(4)));
typedef short s16x8 __attribute__((ext_vector_type(8)));

// ---------------------------------------------------------------------------
// dtype sniff helper: returns 1 if h is fp32 storage, 0 if bf16.
// ---------------------------------------------------------------------------
__device__ __forceinline__ int sniff_fp32(const unsigned short* h_raw) {
  int sane = 0;
#pragma unroll
  for (int i = 0; i < 128; i += 2) {
    const unsigned short u = h_raw[i];
    const int expo = (u >> 7) & 0xFF;
    if (expo >= 112 && expo <= 143) sane++;
  }
  return (sane >= 40) ? 0 : 1;
}

// ---------------------------------------------------------------------------
// Kernel 1: W^T staging (self-sniffing).  Wt[n][k] bf16, n in [0,384),
// padded stride KP.  Block 0 publishes the dtype flag and zeroes
// bucket_cur (258 ints) -- no memset launch on the hot path.
// ---------------------------------------------------------------------------
__global__ __launch_bounds__(128) void wt_kernel(
    const unsigned short* __restrict__ h_raw,
    const void* __restrict__ Wq, const void* __restrict__ Wk,
    const void* __restrict__ Wv, __hip_bfloat16* __restrict__ Wt,
    int* __restrict__ flag, int* __restrict__ bucket_cur) {
  const int isf = sniff_fp32(h_raw);  // block-uniform, ~64 L2-hit loads
  const int n = blockIdx.x;
  const int k = threadIdx.x;
  if (n == 0) {
    if (k == 0) *flag = isf;
    for (int j = k; j < 258; j += 128) bucket_cur[j] = 0;
  }
  const int mat = n >> 7;
  const int col = n & 127;
  const void* W = (mat == 0) ? Wq : (mat == 1) ? Wk : Wv;
  float v;
  if (isf) v = ((const float*)W)[(size_t)k * HD + col];
  else     v = __bfloat162float(((const __hip_bfloat16*)W)[(size_t)k * HD + col]);
  Wt[(size_t)n * KP + k] = __float2bfloat16(v);
}

// ---------------------------------------------------------------------------
// Kernel 2 (fused, round-10): blocks [0, nchunkB) = capacity-slotted
// bucketize; blocks [nchunkB, nchunkB+pgrid) = MFMA projection with
// MT=32 (1563 proj blocks -> ~7.6 blocks/CU resident vs 4.6 at MT=64).
// Wave split: rg = wave&1 owns 16 rows, th = wave>>1 owns 4 t-tiles;
// each wave runs all 3 matrices.  B-fragments read directly from the
// L2-resident Wt (no LDS staging).  As = 8.7 KB.
// ---------------------------------------------------------------------------
__global__ __launch_bounds__(256, 4) void proj_bucketize_kernel(
    const void* __restrict__ h, const __hip_bfloat16* __restrict__ Wt,
    const void* __restrict__ bq, const void* __restrict__ bk,
    const void* __restrict__ bv,
    __hip_bfloat16* __restrict__ Qb, __hip_bfloat16* __restrict__ KVb,
    const int* __restrict__ flag, int n_nodes,
    const int* __restrict__ src, const int* __restrict__ dst,
    int* __restrict__ bucket_cur, unsigned int* __restrict__ ebuf,
    int ecap, int n_edges, int nchunkB) {
  __shared__ short As[MT * KP];   // 8704 B
  __shared__ int lh[256];

  const int tid = threadIdx.x;

  if (blockIdx.x < nchunkB) {
    // ---- bucketize role (capacity-slotted, runs concurrent with proj) ----
    const int e0 = blockIdx.x * BCHUNK;
    const int e1 = (e0 + BCHUNK < n_edges) ? e0 + BCHUNK : n_edges;
    lh[tid] = 0;
    __syncthreads();
    for (int e = e0 + tid; e < e1; e += 256) atomicAdd(&lh[dst[e] >> 8], 1);
    __syncthreads();
    const int cnt_local = lh[tid];
    int base = 0;
    if (cnt_local > 0)
      base = tid * ecap + atomicAdd(&bucket_cur[tid], cnt_local);
    __syncthreads();
    lh[tid] = base;
    __syncthreads();
    for (int e = e0 + tid; e < e1; e += 256) {
      const int d = dst[e];
      const int pos = atomicAdd(&lh[d >> 8], 1);
      ebuf[pos] = ((unsigned int)src[e] << 16) | (unsigned int)d;
    }
    return;
  }

  // ---- projection role ----
  const int node0 = (blockIdx.x - nchunkB) * MT;
  const int isf = *flag;

  // stage 32 x 128 bf16 rows of h into As (8 rounds of 256 x 4B)
#pragma unroll
  for (int j = 0; j < 8; ++j) {
    const int pid = tid + j * 256;
    const int m = pid >> 6;
    const int kk = (pid & 63) * 2;
    const int g = node0 + m;
    unsigned int pack = 0;
    if (g < n_nodes) {
      if (isf) {
        const float2 f2 = *(const float2*)((const float*)h + (size_t)g * HD + kk);
        const __hip_bfloat16 b0 = __float2bfloat16(f2.x);
        const __hip_bfloat16 b1 = __float2bfloat16(f2.y);
        pack = (unsigned int)(*(const unsigned short*)&b0) |
               ((unsigned int)(*(const unsigned short*)&b1) << 16);
      } else {
        pack = *(const unsigned int*)((const __hip_bfloat16*)h +
                                      (size_t)g * HD + kk);
      }
    }
    *(unsigned int*)&As[m * KP + kk] = pack;
  }
  __syncthreads();

  const int wave = tid >> 6;
  const int lane = tid & 63;
  const int l15 = lane & 15;
  const int quad = lane >> 4;
  const int rg = wave & 1;    // row group: nodes rg*16 .. rg*16+15
  const int th = wave >> 1;   // t-half: tiles th*4 .. th*4+3

  s16x8 afrag[4];
#pragma unroll
  for (int k4 = 0; k4 < 4; ++k4)
    afrag[k4] = *(const s16x8*)&As[(rg * 16 + l15) * KP + k4 * 32 + quad * 8];

  for (int c = 0; c < 3; ++c) {
    const __hip_bfloat16* Wc = Wt + (size_t)c * NCH * KP;

    f32x4 acc[4];
#pragma unroll
    for (int t = 0; t < 4; ++t) acc[t] = (f32x4){0.f, 0.f, 0.f, 0.f};

#pragma unroll
    for (int t = 0; t < 4; ++t) {
      const int tt = th * 4 + t;
#pragma unroll
      for (int k4 = 0; k4 < 4; ++k4) {
        const s16x8 bfrag = *(const s16x8*)(
            Wc + (tt * 16 + l15) * KP + k4 * 32 + quad * 8);
        acc[t] = __builtin_amdgcn_mfma_f32_16x16x32_bf16(afrag[k4], bfrag,
                                                         acc[t], 0, 0, 0);
      }
    }

    const void* bp = (c == 0) ? bq : (c == 1) ? bk : bv;
#pragma unroll
    for (int t = 0; t < 4; ++t) {
      const int ncol = (th * 4 + t) * 16 + l15;
      const float bias = isf ? ((const float*)bp)[ncol]
                             : __bfloat162float(((const __hip_bfloat16*)bp)[ncol]);
#pragma unroll
      for (int r = 0; r < 4; ++r) {
        const int g = node0 + rg * 16 + quad * 4 + r;
        if (g < n_nodes) {
          const float val = acc[t][r] + bias;
          if (c == 0) {
            Qb[(size_t)g * HD + ncol] = __float2bfloat16(val);
          } else if (c == 1) {
            KVb[(size_t)g * 256 + ncol] = __float2bfloat16(val);
          } else {
            KVb[(size_t)g * 256 + 128 + ncol] = __float2bfloat16(val);
          }
        }
      }
    }
  }
}

// ---------------------------------------------------------------------------
// Fused pass B: per-bucket count -> LDS scan -> row_ptr -> LDS-cursor
// scatter (round-10: 1024 threads -> serial loop depth halved again).
// Bucket sizes from bucket_cur; bucket b's edges at ebuf[b*ecap ...).
// ---------------------------------------------------------------------------
__global__ __launch_bounds__(1024) void bucket_csr_kernel(
    const unsigned int* __restrict__ ebuf, const int* __restrict__ bucket_cur,
    int* __restrict__ row_ptr, int* __restrict__ edge_src,
    int n_nodes, int nbuck, int ecap, int n_edges) {
  __shared__ int lc[256];
  __shared__ int sh[256];
  const int b = blockIdx.x;
  const int t = threadIdx.x;

  // exclusive scan of bucket sizes to find this bucket's output base
  int v = 0;
  if (t < 256) {
    v = (t < nbuck) ? bucket_cur[t] : 0;
    sh[t] = v;
  }
  __syncthreads();
  for (int off = 1; off < 256; off <<= 1) {
    int add = 0;
    if (t < 256 && t >= off) add = sh[t - off];
    __syncthreads();
    if (t < 256) sh[t] += add;
    __syncthreads();
  }
  if (t < 256) lc[t] = sh[t] - v;  // publish exclusive prefixes
  __syncthreads();
  const int lo_out = lc[b];              // base in edge_src (global CSR)
  const int size_b = bucket_cur[b];
  const int lo_in = b * ecap;            // base in ebuf (capacity slot)
  const int nbase = b << 8;
  __syncthreads();

  if (t < 256) lc[t] = 0;
  __syncthreads();
  for (int i = t; i < size_b; i += 1024)
    atomicAdd(&lc[(ebuf[lo_in + i] & 0xFFFFu) - nbase], 1);
  __syncthreads();

  int v2 = 0;
  if (t < 256) {
    v2 = lc[t];
    sh[t] = v2;
  }
  __syncthreads();
  for (int off = 1; off < 256; off <<= 1) {
    int add = 0;
    if (t < 256 && t >= off) add = sh[t - off];
    __syncthreads();
    if (t < 256) sh[t] += add;
    __syncthreads();
  }
  const int excl = (t < 256) ? (sh[t] - v2) : 0;

  if (t < 256) {
    const int node = nbase + t;
    if (node < n_nodes) row_ptr[node] = lo_out + excl;
    if (b == nbuck - 1 && t == 255) row_ptr[n_nodes] = n_edges;
  }
  __syncthreads();
  if (t < 256) lc[t] = lo_out + excl;
  __syncthreads();
  for (int i = t; i < size_b; i += 1024) {
    const unsigned int pkd = ebuf[lo_in + i];
    const int pos = atomicAdd(&lc[(pkd & 0xFFFFu) - nbase], 1);
    edge_src[pos] = (int)(pkd >> 16);
  }
}

// ---------------------------------------------------------------------------
// Fallback CSR build (n_nodes > 65536): direct hist + scans + scatter.
// ---------------------------------------------------------------------------
__global__ __launch_bounds__(256) void hist_kernel(
    const int* __restrict__ dst, int* __restrict__ cnt, int n_edges) {
  const int e = blockIdx.x * blockDim.x + threadIdx.x;
  if (e < n_edges) atomicAdd(&cnt[dst[e]], 1);
}

__global__ __launch_bounds__(256) void scatter_kernel(
    const int* __restrict__ src, const int* __restrict__ dst,
    int* __restrict__ cursor, int* __restrict__ edge_src, int n_edges) {
  const int e = blockIdx.x * blockDim.x + threadIdx.x;
  if (e < n_edges) {
    const int pos = atomicAdd(&cursor[dst[e]], 1);
    edge_src[pos] = src[e];
  }
}

__global__ __launch_bounds__(SCAN_B) void scan1_kernel(
    const int* __restrict__ cnt, int* __restrict__ exs,
    int* __restrict__ bsum, int n) {
  __shared__ int sh[SCAN_B];
  const int t = threadIdx.x;
  const int i = blockIdx.x * SCAN_B + t;
  int v = (i < n) ? cnt[i] : 0;
  sh[t] = v;
  __syncthreads();
  for (int off = 1; off < SCAN_B; off <<= 1) {
    int add = (t >= off) ? sh[t - off] : 0;
    __syncthreads();
    sh[t] += add;
    __syncthreads();
  }
  if (i < n) exs[i] = sh[t] - v;
  if (t == SCAN_B - 1) bsum[blockIdx.x] = sh[t];
}

__global__ __launch_bounds__(SCAN_B) void scan2_kernel(int* __restrict__ bsum,
                                                       int nb) {
  __shared__ int sh[SCAN_B];
  const int t = threadIdx.x;
  if (nb <= SCAN_B) {
    int v = (t < nb) ? bsum[t] : 0;
    sh[t] = v;
    __syncthreads();
    for (int off = 1; off < SCAN_B; off <<= 1) {
      int add = (t >= off) ? sh[t - off] : 0;
      __syncthreads();
      sh[t] += add;
      __syncthreads();
    }
    if (t < nb) bsum[t] = sh[t] - v;
  } else if (t == 0) {
    int run = 0;
    for (int b = 0; b < nb; ++b) { int v = bsum[b]; bsum[b] = run; run += v; }
  }
}

__global__ __launch_bounds__(SCAN_B) void scan3_kernel(
    const int* __restrict__ exs, const int* __restrict__ bsum,
    int* __restrict__ row_ptr, int* __restrict__ cursor, int n, int n_edges) {
  const int i = blockIdx.x * SCAN_B + threadIdx.x;
  if (i < n) {
    const int v = exs[i] + bsum[blockIdx.x];
    row_ptr[i] = v;
    cursor[i] = v;
  }
  if (i == 0) row_ptr[n] = n_edges;
}

// ---------------------------------------------------------------------------
// Kernel 3: per-destination gather (unchanged control; split into two
// unequal dispatches -- measured free, keeps middle kernels visible).
// ---------------------------------------------------------------------------
__global__ __launch_bounds__(128) void gather_kernel(
    const int* __restrict__ row_ptr, const int* __restrict__ edge_src,
    const __hip_bfloat16* __restrict__ Qb, const __hip_bfloat16* __restrict__ KVb,
    void* __restrict__ out, const int* __restrict__ flag, int n_nodes,
    int node0) {
  __shared__ float vred[HD][17];   // channel-major partials, pad 17 (8704B)
  __shared__ float zred[16][HH];   // edge-slot x head z partials

  const int d = node0 + blockIdx.x;
  const int tid = threadIdx.x;

  const int eloc = tid >> 3;   // edge slot 0..15
  const int hh8  = tid & 7;    // head 0..7

  const int start = row_ptr[d];
  const int deg = row_ptr[d + 1] - start;

  // Q row slice for this head (bf16 -> f32), pre-scaled by 1/sqrt(D)
  float qreg[16];
  {
    const uint4* qp = (const uint4*)(Qb + (size_t)d * HD + hh8 * 16);
    unsigned int qw[8];
    *(uint4*)&qw[0] = qp[0];
    *(uint4*)&qw[4] = qp[1];
#pragma unroll
    for (int i = 0; i < 8; ++i) {
      qreg[2 * i]     = __uint_as_float(qw[i] << 16) * 0.25f;
      qreg[2 * i + 1] = __uint_as_float(qw[i] & 0xFFFF0000u) * 0.25f;
    }
  }

  float acc[16];
#pragma unroll
  for (int j = 0; j < 16; ++j) acc[j] = 0.0f;
  float zacc = 0.0f;

  // prefetch both edge slots' src indices
  int s0 = 0, s1 = 0;
  if (eloc < deg) s0 = edge_src[start + eloc];
  if (eloc + 16 < deg) s1 = edge_src[start + eloc + 16];

  for (int ei = eloc; ei < deg; ei += 32) {
    const int sA = s0;
    const bool hasB = (ei + 16 < deg);
    const int sB = hasB ? s1 : sA;  // clamp to a valid row for the loads

    const int nx = ei + 32;
    if (nx < deg) s0 = edge_src[start + nx];
    if (nx + 16 < deg) s1 = edge_src[start + nx + 16];

    // issue all 8 x 16B loads up front (K and V interleaved per node).
    const uint4* pA = (const uint4*)(KVb + (size_t)sA * 256 + hh8 * 16);
    const uint4* pB = (const uint4*)(KVb + (size_t)sB * 256 + hh8 * 16);
    const uint4 kA0 = pA[0], kA1 = pA[1];
    const uint4 vA0 = pA[16], vA1 = pA[17];  // +128 bf16 = +256B = +16 uint4
    const uint4 kB0 = pB[0], kB1 = pB[1];
    const uint4 vB0 = pB[16], vB1 = pB[17];

    unsigned int kw[8];
    *(uint4*)&kw[0] = kA0;
    *(uint4*)&kw[4] = kA1;
    float dotA = 0.0f;
#pragma unroll
    for (int i = 0; i < 8; ++i) {
      const float klo = __uint_as_float(kw[i] << 16);
      const float khi = __uint_as_float(kw[i] & 0xFFFF0000u);
      dotA = fmaf(qreg[2 * i], klo, dotA);
      dotA = fmaf(qreg[2 * i + 1], khi, dotA);
    }
    *(uint4*)&kw[0] = kB0;
    *(uint4*)&kw[4] = kB1;
    float dotB = 0.0f;
#pragma unroll
    for (int i = 0; i < 8; ++i) {
      const float klo = __uint_as_float(kw[i] << 16);
      const float khi = __uint_as_float(kw[i] & 0xFFFF0000u);
      dotB = fmaf(qreg[2 * i], klo, dotB);
      dotB = fmaf(qreg[2 * i + 1], khi, dotB);
    }
    const float scoreA = __expf(fminf(fmaxf(dotA, -5.0f), 5.0f));
    float scoreB = __expf(fminf(fmaxf(dotB, -5.0f), 5.0f));
    if (!hasB) scoreB = 0.0f;
    zacc += scoreA + scoreB;

    unsigned int vwA[8], vwB[8];
    *(uint4*)&vwA[0] = vA0;
    *(uint4*)&vwA[4] = vA1;
    *(uint4*)&vwB[0] = vB0;
    *(uint4*)&vwB[4] = vB1;
#pragma unroll
    for (int i = 0; i < 8; ++i) {
      const float vAlo = __uint_as_float(vwA[i] << 16);
      const float vAhi = __uint_as_float(vwA[i] & 0xFFFF0000u);
      const float vBlo = __uint_as_float(vwB[i] << 16);
      const float vBhi = __uint_as_float(vwB[i] & 0xFFFF0000u);
      acc[2 * i]     = fmaf(scoreA, vAlo, acc[2 * i]);
      acc[2 * i]     = fmaf(scoreB, vBlo, acc[2 * i]);
      acc[2 * i + 1] = fmaf(scoreA, vAhi, acc[2 * i + 1]);
      acc[2 * i + 1] = fmaf(scoreB, vBhi, acc[2 * i + 1]);
    }
  }

  // publish partials channel-major
#pragma unroll
  for (int j = 0; j < 16; ++j) vred[hh8 * 16 + j][eloc] = acc[j];
  zred[eloc][hh8] = zacc;
  __syncthreads();

  // thread = output channel tid; reduce over 16 edge slots
  const int hd16 = tid >> 4;
  float sumV = 0.0f;
#pragma unroll
  for (int i = 0; i < 16; ++i) sumV += vred[tid][i];
  float sumZ = 0.0f;
#pragma unroll
  for (int i = 0; i < 16; ++i) sumZ += zred[i][hd16];

  const float r = sumV / (sumZ + 1e-6f);
  const size_t o = (size_t)d * HD + tid;
  if (*flag) ((float*)out)[o] = r;
  else       ((__hip_bfloat16*)out)[o] = __float2bfloat16(r);
}

// ---------------------------------------------------------------------------
extern "C" void kernel_launch(void* const* d_in, const int* in_sizes, int n_in,
                              void* d_out, int out_size, void* d_ws, size_t ws_size,
                              hipStream_t stream) {
  const void* h  = d_in[0];
  const void* Wq = d_in[1];
  const void* bq = d_in[2];
  const void* Wk = d_in[3];
  const void* bk = d_in[4];
  const void* Wv = d_in[5];
  const void* bv = d_in[6];
  const int* src = (const int*)d_in[7];
  const int* dst = (const int*)d_in[8];

  const int n_nodes = in_sizes[0] / IN_DIM;  // 50000
  const int n_edges = in_sizes[7];           // 1600000
  const int nb = (n_nodes + SCAN_B - 1) / SCAN_B;
  const int nbuck = (n_nodes + 255) >> 8;

  // bucket capacity slot: 2x mean size, 256-aligned, >= 4096
  int ecap = ((2 * (n_edges / (nbuck > 0 ? nbuck : 1)) + 255) / 256) * 256;
  if (ecap < 4096) ecap = 4096;

  // workspace layout (256B-aligned chunks)
  char* p = (char*)d_ws;
  int* flag = (int*)p;                       p += 256;
  __hip_bfloat16* Qb = (__hip_bfloat16*)p;   p += (size_t)n_nodes * HD * 2;
  __hip_bfloat16* KVb = (__hip_bfloat16*)p;  p += (size_t)n_nodes * 256 * 2;
  __hip_bfloat16* Wt = (__hip_bfloat16*)p;   p += ((size_t)384 * KP * 2 + 255) / 256 * 256;
  int* bucket_cur = (int*)p;                 p += 258 * 4 + 248;  // 256B-align next
  int* row_ptr = (int*)p;                    p += (size_t)(n_nodes + 1 + 63) / 64 * 64 * 4;
  int* edge_src = (int*)p;                   p += (size_t)n_edges * 4;
  unsigned int* ebuf = (unsigned int*)p;     p += (size_t)nbuck * ecap * 4;
  // fallback-only arrays
  int* cnt = (int*)p;                        p += (size_t)n_nodes * 4;
  int* exs = (int*)p;                        p += (size_t)n_nodes * 4;
  int* bsum = (int*)p;                       p += (size_t)(nb + 1) * 4;
  int* cursor = (int*)p;                     p += (size_t)n_nodes * 4;

  // wt: self-sniffs, publishes flag, zeroes bucket_cur
  wt_kernel<<<384, 128, 0, stream>>>((const unsigned short*)h, Wq, Wk, Wv, Wt,
                                     flag, bucket_cur);

  const int pgrid = (n_nodes + MT - 1) / MT;
  const int nchunkB = (n_edges + BCHUNK - 1) / BCHUNK;

  if (n_nodes <= 65536) {
    // fused bucketize-first + proj (bucketize co-runs with proj from t=0)
    proj_bucketize_kernel<<<nchunkB + pgrid, 256, 0, stream>>>(
        h, Wt, bq, bk, bv, Qb, KVb, flag, n_nodes, src, dst, bucket_cur,
        ebuf, ecap, n_edges, nchunkB);
    bucket_csr_kernel<<<nbuck, 1024, 0, stream>>>(ebuf, bucket_cur, row_ptr,
                                                  edge_src, n_nodes, nbuck,
                                                  ecap, n_edges);
  } else {
    // fallback: proj alone (nchunkB=0), then direct hist + scans + scatter
    proj_bucketize_kernel<<<pgrid, 256, 0, stream>>>(
        h, Wt, bq, bk, bv, Qb, KVb, flag, n_nodes, src, dst, bucket_cur,
        ebuf, ecap, n_edges, 0);
    hipMemsetAsync(cnt, 0, (size_t)n_nodes * sizeof(int), stream);
    const int eb = 256;
    const int egrid = (n_edges + eb - 1) / eb;
    hist_kernel<<<egrid, eb, 0, stream>>>(dst, cnt, n_edges);
    scan1_kernel<<<nb, SCAN_B, 0, stream>>>(cnt, exs, bsum, n_nodes);
    scan2_kernel<<<1, SCAN_B, 0, stream>>>(bsum, nb);
    scan3_kernel<<<nb, SCAN_B, 0, stream>>>(exs, bsum, row_ptr, cursor,
                                            n_nodes, n_edges);
    scatter_kernel<<<egrid, eb, 0, stream>>>(src, dst, cursor, edge_src,
                                             n_edges);
  }

  // gather split into two unequal dispatches (measured free; keeps middle
  // kernels visible in the profiler's top-5)
  if (n_nodes > 20000) {
    const int split = 18000;
    gather_kernel<<<split, 128, 0, stream>>>(row_ptr, edge_src, Qb, KVb,
                                             d_out, flag, n_nodes, 0);
    gather_kernel<<<n_nodes - split, 128, 0, stream>>>(
        row_ptr, edge_src, Qb, KVb, d_out, flag, n_nodes, split);
  } else {
    gather_kernel<<<n_nodes, 128, 0, stream>>>(row_ptr, edge_src, Qb, KVb,
                                               d_out, flag, n_nodes, 0);
  }
}